// Round 17
// baseline (385.577 us; speedup 1.0000x reference)
//
#include <hip/hip_runtime.h>

#define B_ 4
#define S_ 2048
#define D_ 1024
#define H_ 16
#define HD_ 64
#define DFF_ 4096
#define MR_ 32
#define M_ (B_*S_)

typedef unsigned short u16;
typedef __attribute__((ext_vector_type(8))) short bf16x8;
typedef __attribute__((ext_vector_type(4))) float f32x4;

#define MFMA16 __builtin_amdgcn_mfma_f32_16x16x32_bf16
#define A_CONST 0.18033688011112f   /* 0.125 * log2(e) */
#define LOG2E_ 1.44269504088896f

__device__ __forceinline__ u16 f2b(float f) {
  unsigned u = __builtin_bit_cast(unsigned, f);
  u = u + 0x7FFFu + ((u >> 16) & 1u);
  return (u16)(u >> 16);
}
__device__ __forceinline__ float b2f(u16 h) {
  unsigned u = ((unsigned)h) << 16;
  return __builtin_bit_cast(float, u);
}
__device__ __forceinline__ float exp2_fast(float x) {
  float r;
  asm("v_exp_f32 %0, %1" : "=v"(r) : "v"(x));
  return r;
}
__device__ __forceinline__ unsigned cvtpk(float lo, float hi) {
  unsigned r;
  asm("v_cvt_pk_bf16_f32 %0, %1, %2" : "=v"(r) : "v"(lo), "v"(hi));
  return r;
}
__device__ __forceinline__ int med3i(int a, int b, int c) {
  int r;
  asm("v_med3_i32 %0, %1, %2, %3" : "=v"(r) : "v"(a), "v"(b), "v"(c));
  return r;
}
// tanh-form GELU: max |diff vs exact erf-GELU| ~2e-4
__device__ __forceinline__ float gelu_t(float v) {
  float v2 = v * v;
  float z  = v * fmaf(v2, 0.1029394f, 2.3021171f);
  float e  = exp2_fast(z);
  float r;
  asm("v_rcp_f32 %0, %1" : "=v"(r) : "v"(e + 1.0f));
  return v - v * r;
}
__device__ __forceinline__ void gl_lds16(const void* g, void* l) {
  __builtin_amdgcn_global_load_lds(
      (const __attribute__((address_space(1))) void*)g,
      (__attribute__((address_space(3))) void*)l, 16, 0, 0);
}

// swizzle for 128B-row tiles (attention)
#define SWZ(r) ((((((r)>>3)&1)<<2) ^ ((r)&7)) << 4)
// swizzle for 64B-row tiles (gemm)
#define SWZ64(r) ((((r)>>1)&3) << 4)

// ========= merged prep: cvt (x->xb) + all 6 weight transposes, ONE launch =========
__global__ __launch_bounds__(256) void prep_kernel(
    const float* __restrict__ x, u16* __restrict__ xb,
    const float* __restrict__ wq, const float* __restrict__ wk,
    const float* __restrict__ wv, const float* __restrict__ wo,
    const float* __restrict__ w1, const float* __restrict__ w2,
    u16* __restrict__ wqT, u16* __restrict__ wkT, u16* __restrict__ wvT,
    u16* __restrict__ woT, u16* __restrict__ w1T, u16* __restrict__ w2T)
{
  int bid = blockIdx.x;
  const int tid = threadIdx.x;
  if (bid < 8192) {
    int i = bid * 256 + tid;
    float4 v = ((const float4*)x)[i];
    ushort4 o;
    o.x = f2b(v.x); o.y = f2b(v.y); o.z = f2b(v.z); o.w = f2b(v.w);
    ((ushort4*)xb)[i] = o;
    return;
  }
  bid -= 8192;
  const float* in; u16* out; int R, C, local;
  if (bid < 4096) {
    int m = bid >> 10;
    in  = m == 0 ? wq  : (m == 1 ? wk  : (m == 2 ? wv  : wo));
    out = m == 0 ? wqT : (m == 1 ? wkT : (m == 2 ? wvT : woT));
    R = 1024; C = 1024; local = bid & 1023;
  } else if (bid < 8192) {
    in = w1; out = w1T; R = 1024; C = 4096; local = bid - 4096;
  } else {
    in = w2; out = w2T; R = 4096; C = 1024; local = bid - 8192;
  }
  const int ctiles = C >> 5;
  const int c0 = (local % ctiles) * 32;
  const int r0 = (local / ctiles) * 32;
  const int xx = tid & 31, yy = tid >> 5;
  __shared__ float t[32][33];
#pragma unroll
  for (int i = 0; i < 4; ++i)
    t[yy + i*8][xx] = in[(long)(r0 + yy + i*8) * C + c0 + xx];
  __syncthreads();
#pragma unroll
  for (int i = 0; i < 4; ++i)
    out[(long)(c0 + yy + i*8) * R + r0 + xx] = f2b(t[xx][yy + i*8]);
}

// ===== gemm13: 8 waves, 64x64/wave, ring-of-4, 3-ahead staging, vmcnt(6) =====
// Deeper prefetch slack (~3 iterations vs 1) to cover L2/HBM latency; single
// barrier per K-step (R14-proven). 96KB LDS -> 1 block/CU.
// EPI: 0 = bf16+bias, 2 = tanh-GELU, 3 = fused-QKV routing (V direct-transposed
//      to C2 = vT [B,H,HD,S]), 4 = bf16+bias+residual(res)
template<int EPI, int WN>
__global__ __launch_bounds__(512, 1) void gemm13(
    const u16* __restrict__ A, const u16* __restrict__ BT,
    const float* __restrict__ bias0, const float* __restrict__ bias1,
    const float* __restrict__ bias2,
    u16* __restrict__ C0, u16* __restrict__ C1, u16* __restrict__ C2,
    const u16* __restrict__ res,
    int Ndim, int Kdim)
{
  constexpr int BM = (WN == 4) ? 128 : 256;
  constexpr int BN = WN * 64;
  constexpr int SLOT = (BM + BN) * 64;   // 24576 bytes
  __shared__ char lds[4 * SLOT];         // ring-4 = 96KB
  const int tid = threadIdx.x;
  const int w = tid >> 6, lane = tid & 63;
  const int lr = lane & 15, lg = lane >> 4;
  const int wm = w / WN, wn = w % WN;

  const int nbx = Ndim / BN;
  const int cpx = gridDim.x >> 3;
  const int bid = blockIdx.x;
  const int swzb = (bid & 7) * cpx + (bid >> 3);
  const long blockM = (long)(swzb / nbx) * BM;
  const long blockN = (long)(swzb % nbx) * BN;

  const int srow = tid >> 2;
  const int scol = ((tid & 3) * 16) ^ SWZ64(srow);
  const u16* Ag  = A  + (blockM + srow) * (long)Kdim + (scol >> 1);
  const u16* Ag2 = Ag + (long)128 * Kdim;
  const u16* Bg  = BT + (blockN + srow) * (long)Kdim + (scol >> 1);
  const u16* Bg2 = Bg + (long)128 * Kdim;

  auto STAGE = [&](int slot, long ko) {   // 3 gl_lds per call (both WN)
    char* base = &lds[slot * SLOT];
    gl_lds16(Ag + ko, base + w * 1024);
    if constexpr (WN == 2) gl_lds16(Ag2 + ko, base + 8192 + w * 1024);
    gl_lds16(Bg + ko, base + BM * 64 + w * 1024);
    if constexpr (WN == 4) gl_lds16(Bg2 + ko, base + BM * 64 + 8192 + w * 1024);
  };

  const int rsw = (lg * 16) ^ SWZ64(lr);
  int offA[4], offB[4];
#pragma unroll
  for (int mf = 0; mf < 4; ++mf) offA[mf] = (wm*64 + mf*16 + lr) * 64 + rsw;
#pragma unroll
  for (int nf = 0; nf < 4; ++nf) offB[nf] = BM*64 + (wn*64 + nf*16 + lr) * 64 + rsw;

  f32x4 acc[4][4] = {};
  const int NS = Kdim >> 5;

  STAGE(0, 0);
  STAGE(1, 32);
  STAGE(2, 64);
  asm volatile("s_waitcnt vmcnt(6)" ::: "memory");   // slice 0 landed
  __builtin_amdgcn_s_barrier();

  for (int t = 0; t < NS; ++t) {
    const char* s = &lds[(t & 3) * SLOT];
    bf16x8 af[4], bfr[4];
#pragma unroll
    for (int mf = 0; mf < 4; ++mf) af[mf] = *(const bf16x8*)(s + offA[mf]);
#pragma unroll
    for (int nf = 0; nf < 4; ++nf) bfr[nf] = *(const bf16x8*)(s + offB[nf]);
    if (t + 3 < NS) {
      STAGE((t + 3) & 3, (long)(t + 3) * 32);
      asm volatile("s_waitcnt vmcnt(6)" ::: "memory");  // slice t+1 landed
    } else if (t == NS - 3) {
      asm volatile("s_waitcnt vmcnt(3)" ::: "memory");  // slice NS-2 landed
    } else if (t == NS - 2) {
      asm volatile("s_waitcnt vmcnt(0)" ::: "memory");  // slice NS-1 landed
    }
    __builtin_amdgcn_s_barrier();   // single barrier per K-step
    __builtin_amdgcn_s_setprio(1);
#pragma unroll
    for (int mf = 0; mf < 4; ++mf)
#pragma unroll
      for (int nf = 0; nf < 4; ++nf)
        acc[mf][nf] = MFMA16(bfr[nf], af[mf], acc[mf][nf], 0, 0, 0);
    __builtin_amdgcn_s_setprio(0);
  }

  const float* bsel = bias0;
  u16* osel = C0;
  long nstride = Ndim;
  long ncol0 = blockN;
  int mat = 0;
  if (EPI == 3) {
    mat = (int)(blockN >> 10);
    bsel = mat == 0 ? bias0 : (mat == 1 ? bias1 : bias2);
    osel = mat == 0 ? C0 : C1;
    nstride = 1024;
    ncol0 = blockN & 1023;
  }
  __syncthreads();   // all waves done with K-loop LDS reads

  if (EPI == 3 && mat == 2) {
    // ---- V: direct transposed store to vT [B,H,HD,S] (C2) ----
#pragma unroll
    for (int mf = 0; mf < 4; ++mf) {
      const int row = wm*64 + mf*16 + lr;
      const long m = blockM + row;
      const long b = m >> 11, sg = m & 2047;
#pragma unroll
      for (int nf = 0; nf < 4; ++nf) {
#pragma unroll
        for (int j = 0; j < 4; ++j) {
          const long colg = ncol0 + wn*64 + nf*16 + lg*4 + j;
          float v = acc[mf][nf][j] + bsel[colg];
          const long h = colg >> 6, hd = colg & 63;
          C2[((b*16 + h)*64 + hd)*2048 + sg] = f2b(v);
        }
      }
    }
    return;
  }

  constexpr int RB = BN * 2;
  char* const et = &lds[0];
#pragma unroll
  for (int mf = 0; mf < 4; ++mf) {
    const int row = wm*64 + mf*16 + lr;
#pragma unroll
    for (int nf = 0; nf < 4; ++nf) {
      const int colu = wn*64 + nf*16 + lg*4;
      float4 bv = *(const float4*)&bsel[ncol0 + colu];
      float v0 = acc[mf][nf][0] + bv.x;
      float v1 = acc[mf][nf][1] + bv.y;
      float v2 = acc[mf][nf][2] + bv.z;
      float v3 = acc[mf][nf][3] + bv.w;
      if (EPI == 2) {
        v0 = gelu_t(v0); v1 = gelu_t(v1); v2 = gelu_t(v2); v3 = gelu_t(v3);
      }
      if (EPI == 4) {
        ushort4 rv = *(const ushort4*)&res[(blockM + row) * 1024 + ncol0 + colu];
        v0 += b2f(rv.x); v1 += b2f(rv.y); v2 += b2f(rv.z); v3 += b2f(rv.w);
      }
      ushort4 st;
      st.x = f2b(v0); st.y = f2b(v1); st.z = f2b(v2); st.w = f2b(v3);
      *(ushort4*)(et + row*RB + ((colu*2) ^ ((row & 7) << 4))) = st;
    }
  }
  __syncthreads();
  constexpr int CHR  = RB / 16;
  constexpr int ITER = BM * CHR / 512;
#pragma unroll
  for (int i = 0; i < ITER; ++i) {
    const int idx = i*512 + tid;
    const int row = idx / CHR;
    const int cb  = (idx % CHR) * 16;
    uint4 val = *(const uint4*)(et + row*RB + (cb ^ ((row & 7) << 4)));
    *(uint4*)&osel[(blockM + row) * nstride + ncol0 + (cb >> 1)] = val;
  }
}

// ========== flash attention v8 (proven 88.6us): QBLK=256 + per-head XCD clustering ==========
__device__ __forceinline__ void packp(const float* p, bf16x8* pfo) {
#pragma unroll
  for (int ks = 0; ks < 2; ++ks) {
    uint4 uu;
    uu.x = cvtpk(p[ks*4+0], p[ks*4+1]);
    uu.y = cvtpk(p[ks*4+2], p[ks*4+3]);
    uu.z = cvtpk(p[(ks+2)*4+0], p[(ks+2)*4+1]);
    uu.w = cvtpk(p[(ks+2)*4+2], p[(ks+2)*4+3]);
    pfo[ks] = __builtin_bit_cast(bf16x8, uu);
  }
}

__device__ __forceinline__ void sm_uni(const f32x4* s, float bu, bf16x8* pfo) {
  float p[16];
#pragma unroll
  for (int ni = 0; ni < 4; ++ni)
#pragma unroll
    for (int j = 0; j < 4; ++j)
      p[ni*4+j] = exp2_fast(fmaf(s[ni][j], A_CONST, bu));
  packp(p, pfo);
}

__device__ __forceinline__ void sm_slow(const f32x4* s, const float* relb,
                                        int rbase, bf16x8* pfo) {
  float p[16];
#pragma unroll
  for (int ni = 0; ni < 4; ++ni) {
    const int koff = (ni&1)*32 + (ni>>1)*4;
#pragma unroll
    for (int j = 0; j < 4; ++j) {
      int idx = med3i(rbase + koff + j + MR_, 0, 2*MR_);
      p[ni*4+j] = exp2_fast(fmaf(s[ni][j], A_CONST, relb[idx]));
    }
  }
  packp(p, pfo);
}

__global__ __launch_bounds__(256, 2) void attn8_kernel(
    const u16* __restrict__ q, const u16* __restrict__ k,
    const u16* __restrict__ vT, const float* __restrict__ rel_pos,
    u16* __restrict__ ao)
{
  __shared__ u16 SM[16384];
  __shared__ float relb[2*MR_ + 1];

  const int tid = threadIdx.x;
  const int w = tid >> 6, lane = tid & 63;
  const int lr = lane & 15, lg = lane >> 4;
  const int bid = blockIdx.x;
  const int bh = ((bid >> 6) << 3) | (bid & 7);
  const int qt = (bid >> 3) & 7;
  const int b = bh >> 4, h = bh & 15;
  const int q0 = qt * 256;
  const int qlo = q0 + w*64;

  if (tid < 2*MR_ + 1) relb[tid] = rel_pos[h * (2*MR_ + 1) + tid] * LOG2E_;

  const int srow0 = w*8 + (lane >> 3);
  const int srow1 = 32 + srow0;
  const int scb   = (lane & 7) * 16;
  const int col0  = scb ^ SWZ(srow0);
  const int col1  = scb ^ SWZ(srow1);

  const long qkbase = ((long)(b*S_)) * D_ + h*64;
  const long vbase  = ((long)((b*H_ + h) * HD_)) * S_;

  {
    const u16* qg = q + qkbase + (long)q0 * D_;
#pragma unroll
    for (int c = 0; c < 8; ++c)
      gl_lds16(qg + (long)(c*32 + srow0)*D_ + (col0 >> 1), &SM[(c*32 + w*8)*64]);
  }
  __syncthreads();
  bf16x8 qf[4][2];
#pragma unroll
  for (int qi = 0; qi < 4; ++qi)
#pragma unroll
    for (int ks = 0; ks < 2; ++ks) {
      int row = w*64 + qi*16 + lr;
      qf[qi][ks] = *(const bf16x8*)((const char*)&SM[0] + row*128 + ((ks*64 + lg*16) ^ SWZ(row)));
    }
  const float bHI = relb[2*MR_];
  const float bLO = relb[0];
  __syncthreads();

  int offK0[4], offV0[4];
#pragma unroll
  for (int ni = 0; ni < 4; ++ni) {
    int kr = (ni&1)*32 + (lr>>2)*8 + (ni>>1)*4 + (lr&3);  // kappa(ni, lr)
    int vr = ni*16 + lr;
    offK0[ni] = kr*128 + ((lg*16) ^ SWZ(kr));
    offV0[ni] = vr*128 + ((lg*16) ^ SWZ(vr));
  }

  const u16* kp0 = k  + qkbase + (long)srow0*D_ + (col0 >> 1);
  const u16* kp1 = k  + qkbase + (long)srow1*D_ + (col1 >> 1);
  const u16* vp0 = vT + vbase  + (long)srow0*S_ + (col0 >> 1);
  const u16* vp1 = vT + vbase  + (long)srow1*S_ + (col1 >> 1);
  u16* kb_w0 = &SM[(w*8)*64];
  u16* kb_w1 = &SM[(32 + w*8)*64];
  u16* vb_w0 = &SM[8192 + (w*8)*64];
  u16* vb_w1 = &SM[8192 + (32 + w*8)*64];

  bf16x8 onesf;
#pragma unroll
  for (int i = 0; i < 8; ++i) onesf[i] = (short)0x3F80;

  f32x4 acco[4][4] = {};
  f32x4 accl[4] = {};

  gl_lds16(kp0, kb_w0);
  gl_lds16(kp1, kb_w1);
  gl_lds16(vp0, vb_w0);
  gl_lds16(vp1, vb_w1);

  const long kstep = (long)64 * D_;
  const int NT = S_ / 64;
  for (int t = 0; t < NT; ++t) {
    const int cur = t & 1;
    __syncthreads();
    if (t + 1 < NT) {
      int bufo = (cur ^ 1) * 4096;
      gl_lds16(kp0 + (long)(t+1)*kstep, kb_w0 + bufo);
      gl_lds16(kp1 + (long)(t+1)*kstep, kb_w1 + bufo);
      gl_lds16(vp0 + (t+1)*64, vb_w0 + bufo);
      gl_lds16(vp1 + (t+1)*64, vb_w1 + bufo);
    }
    const char* Kb = (const char*)&SM[cur * 4096];
    const char* Vb = (const char*)&SM[8192 + cur * 4096];
    const int k0 = t * 64;

    f32x4 sc[4][4] = {};
#pragma unroll
    for (int ks = 0; ks < 2; ++ks)
#pragma unroll
      for (int ni = 0; ni < 4; ++ni) {
        bf16x8 kf = *(const bf16x8*)(Kb + (offK0[ni] ^ (ks*64)));
#pragma unroll
        for (int qi = 0; qi < 4; ++qi)
          sc[qi][ni] = MFMA16(kf, qf[qi][ks], sc[qi][ni], 0, 0, 0);
      }

    bf16x8 pf[4][2];
    bool hi_u = (k0 - (qlo + 63)) >= MR_;
    bool lo_u = (qlo - (k0 + 63)) >= MR_;
    if (hi_u || lo_u) {
      float bu = hi_u ? bHI : bLO;
#pragma unroll
      for (int qi = 0; qi < 4; ++qi) sm_uni(sc[qi], bu, pf[qi]);
    } else {
      int rb0 = k0 + lg*8 - (qlo + lr);
#pragma unroll
      for (int qi = 0; qi < 4; ++qi) sm_slow(sc[qi], relb, rb0 - qi*16, pf[qi]);
    }

#pragma unroll
    for (int ks = 0; ks < 2; ++ks) {
#pragma unroll
      for (int ni = 0; ni < 4; ++ni) {
        bf16x8 vf = *(const bf16x8*)(Vb + (offV0[ni] ^ (ks*64)));
#pragma unroll
        for (int qi = 0; qi < 4; ++qi)
          acco[qi][ni] = MFMA16(vf, pf[qi][ks], acco[qi][ni], 0, 0, 0);
      }
#pragma unroll
      for (int qi = 0; qi < 4; ++qi)
        accl[qi] = MFMA16(onesf, pf[qi][ks], accl[qi], 0, 0, 0);
    }
  }

#pragma unroll
  for (int qi = 0; qi < 4; ++qi) {
    float inv = 1.0f / accl[qi][0];
    long orow = ((long)(b*S_ + qlo + qi*16 + lr)) * D_ + h*64;
#pragma unroll
    for (int ni = 0; ni < 4; ++ni) {
      ushort4 ov;
      ov.x = f2b(acco[qi][ni][0] * inv);
      ov.y = f2b(acco[qi][ni][1] * inv);
      ov.z = f2b(acco[qi][ni][2] * inv);
      ov.w = f2b(acco[qi][ni][3] * inv);
      *(ushort4*)(ao + orow + ni*16 + lg*4) = ov;
    }
  }
}

// ------------- single-input RMSNorm (input already includes residual) -------------
template<int OUTF>
__global__ __launch_bounds__(256) void rms1_kernel(
    const u16* __restrict__ a, const float* __restrict__ g,
    float* __restrict__ outf, u16* __restrict__ outb)
{
  long row = blockIdx.x;
  int tid = threadIdx.x;
  ushort4 av = ((const ushort4*)a)[row*256 + tid];
  float y[4] = { b2f(av.x), b2f(av.y), b2f(av.z), b2f(av.w) };
  float ss = 0.f;
#pragma unroll
  for (int i = 0; i < 4; ++i) ss += y[i]*y[i];
#pragma unroll
  for (int m = 1; m < 64; m <<= 1) ss += __shfl_xor(ss, m);
  __shared__ float red[4];
  int w = tid >> 6, lane = tid & 63;
  if (lane == 0) red[w] = ss;
  __syncthreads();
  ss = red[0] + red[1] + red[2] + red[3];
  float rinv = rsqrtf(ss * (1.0f / D_) + 1e-5f);
  float4 gv = ((const float4*)g)[tid];
  float o[4] = { y[0]*rinv*gv.x, y[1]*rinv*gv.y, y[2]*rinv*gv.z, y[3]*rinv*gv.w };
  if (OUTF) {
    float4 of = { o[0], o[1], o[2], o[3] };
    ((float4*)outf)[row*256 + tid] = of;
  } else {
    ushort4 ob;
    ob.x = f2b(o[0]); ob.y = f2b(o[1]); ob.z = f2b(o[2]); ob.w = f2b(o[3]);
    ((ushort4*)outb)[row*256 + tid] = ob;
  }
}

extern "C" void kernel_launch(void* const* d_in, const int* in_sizes, int n_in,
                              void* d_out, int out_size, void* d_ws, size_t ws_size,
                              hipStream_t stream) {
  const float* x   = (const float*)d_in[0];
  const float* g1  = (const float*)d_in[1];
  const float* g2  = (const float*)d_in[2];
  const float* wq  = (const float*)d_in[3];
  const float* bq  = (const float*)d_in[4];
  const float* wk  = (const float*)d_in[5];
  const float* bk  = (const float*)d_in[6];
  const float* wv  = (const float*)d_in[7];
  const float* bv  = (const float*)d_in[8];
  const float* wo  = (const float*)d_in[9];
  const float* bo  = (const float*)d_in[10];
  const float* rel = (const float*)d_in[11];
  const float* w1  = (const float*)d_in[12];
  const float* b1  = (const float*)d_in[13];
  const float* w2  = (const float*)d_in[14];
  const float* b2  = (const float*)d_in[15];
  float* out = (float*)d_out;

  char* ws = (char*)d_ws;
  const size_t MB = 1024ull * 1024ull;
  u16* xb   = (u16*)(ws + 0);        // 16 MB
  u16* wqT  = (u16*)(ws + 16*MB);    // 2  } contiguous [3072][1024]
  u16* wkT  = (u16*)(ws + 18*MB);    // 2  }
  u16* wvT  = (u16*)(ws + 20*MB);    // 2  }
  u16* woT  = (u16*)(ws + 22*MB);    // 2
  u16* w1T  = (u16*)(ws + 24*MB);    // 8
  u16* w2T  = (u16*)(ws + 32*MB);    // 8
  u16* qb   = (u16*)(ws + 40*MB);    // 16
  u16* kb   = (u16*)(ws + 56*MB);    // 16
  u16* vTb  = (u16*)(ws + 88*MB);    // 16 (written directly by QKV epilogue)
  u16* aob  = (u16*)(ws + 104*MB);   // 16
  u16* prjb = (u16*)(ws + 120*MB);   // 16  (= proj + x, residual fused)
  u16* x1b  = (u16*)(ws + 136*MB);   // 16
  u16* hb   = (u16*)(ws + 40*MB);    // 64, reuses q/k/vT (dead after attention)
  u16* ffb  = (u16*)(ws + 120*MB);   // 16, reuses prjb (= ff + x1, residual fused)
  (void)ws_size; (void)in_sizes; (void)n_in; (void)out_size;

  // 1. merged prep: cvt + all 6 weight transposes (one launch)
  prep_kernel<<<20480, 256, 0, stream>>>(
      x, xb, wq, wk, wv, wo, w1, w2, wqT, wkT, wvT, woT, w1T, w2T);

  // 2. fused QKV projection; V stored transposed directly to vTb
  gemm13<3,4><<<(3072/256)*(M_/128), 512, 0, stream>>>(
      xb, wqT, bq, bk, bv, qb, kb, vTb, nullptr, 3072, D_);

  // 3. attention: QBLK=256, 1D grid 512, per-head XCD clustering
  attn8_kernel<<<512, 256, 0, stream>>>(qb, kb, vTb, rel, aob);

  // 4. output projection + residual(xb): prjb = ao@wo + bo + x
  gemm13<4,2><<<(D_/128)*(M_/256), 512, 0, stream>>>(
      aob, woT, bo, nullptr, nullptr, prjb, nullptr, nullptr, xb, D_, D_);

  // 5. x1 = rmsnorm(prjb, g1) -> bf16
  rms1_kernel<0><<<M_, 256, 0, stream>>>(prjb, g1, nullptr, x1b);

  // 6. h = gelu(x1 @ w1 + b1): BM=128, BN=256, grid 1024
  gemm13<2,4><<<(DFF_/256)*(M_/128), 512, 0, stream>>>(
      x1b, w1T, b1, nullptr, nullptr, hb, nullptr, nullptr, nullptr, DFF_, D_);

  // 7. ffb = h @ w2 + b2 + x1 (residual fused)
  gemm13<4,2><<<(D_/128)*(M_/256), 512, 0, stream>>>(
      hb, w2T, b2, nullptr, nullptr, ffb, nullptr, nullptr, x1b, D_, DFF_);

  // 8. out = rmsnorm(ffb, g2) -> f32 d_out
  rms1_kernel<1><<<M_, 256, 0, stream>>>(ffb, g2, out, nullptr);
}

// Round 18
// 372.230 us; speedup vs baseline: 1.0359x; 1.0359x over previous
//
#include <hip/hip_runtime.h>

#define B_ 4
#define S_ 2048
#define D_ 1024
#define H_ 16
#define HD_ 64
#define DFF_ 4096
#define MR_ 32
#define M_ (B_*S_)

typedef unsigned short u16;
typedef __attribute__((ext_vector_type(8))) short bf16x8;
typedef __attribute__((ext_vector_type(4))) float f32x4;

#define MFMA16 __builtin_amdgcn_mfma_f32_16x16x32_bf16
#define A_CONST 0.18033688011112f   /* 0.125 * log2(e) */
#define LOG2E_ 1.44269504088896f

__device__ __forceinline__ u16 f2b(float f) {
  unsigned u = __builtin_bit_cast(unsigned, f);
  u = u + 0x7FFFu + ((u >> 16) & 1u);
  return (u16)(u >> 16);
}
__device__ __forceinline__ float b2f(u16 h) {
  unsigned u = ((unsigned)h) << 16;
  return __builtin_bit_cast(float, u);
}
__device__ __forceinline__ float exp2_fast(float x) {
  float r;
  asm("v_exp_f32 %0, %1" : "=v"(r) : "v"(x));
  return r;
}
__device__ __forceinline__ unsigned cvtpk(float lo, float hi) {
  unsigned r;
  asm("v_cvt_pk_bf16_f32 %0, %1, %2" : "=v"(r) : "v"(lo), "v"(hi));
  return r;
}
__device__ __forceinline__ int med3i(int a, int b, int c) {
  int r;
  asm("v_med3_i32 %0, %1, %2, %3" : "=v"(r) : "v"(a), "v"(b), "v"(c));
  return r;
}
// tanh-form GELU: max |diff vs exact erf-GELU| ~2e-4
__device__ __forceinline__ float gelu_t(float v) {
  float v2 = v * v;
  float z  = v * fmaf(v2, 0.1029394f, 2.3021171f);
  float e  = exp2_fast(z);
  float r;
  asm("v_rcp_f32 %0, %1" : "=v"(r) : "v"(e + 1.0f));
  return v - v * r;
}
__device__ __forceinline__ void gl_lds16(const void* g, void* l) {
  __builtin_amdgcn_global_load_lds(
      (const __attribute__((address_space(1))) void*)g,
      (__attribute__((address_space(3))) void*)l, 16, 0, 0);
}

// swizzle for 128B-row tiles (attention)
#define SWZ(r) ((((((r)>>3)&1)<<2) ^ ((r)&7)) << 4)
// swizzle for 64B-row tiles (gemm)
#define SWZ64(r) ((((r)>>1)&3) << 4)

// ========= merged prep: cvt (x->xb) + all 6 weight transposes, ONE launch =========
__global__ __launch_bounds__(256) void prep_kernel(
    const float* __restrict__ x, u16* __restrict__ xb,
    const float* __restrict__ wq, const float* __restrict__ wk,
    const float* __restrict__ wv, const float* __restrict__ wo,
    const float* __restrict__ w1, const float* __restrict__ w2,
    u16* __restrict__ wqT, u16* __restrict__ wkT, u16* __restrict__ wvT,
    u16* __restrict__ woT, u16* __restrict__ w1T, u16* __restrict__ w2T)
{
  int bid = blockIdx.x;
  const int tid = threadIdx.x;
  if (bid < 8192) {
    int i = bid * 256 + tid;
    float4 v = ((const float4*)x)[i];
    ushort4 o;
    o.x = f2b(v.x); o.y = f2b(v.y); o.z = f2b(v.z); o.w = f2b(v.w);
    ((ushort4*)xb)[i] = o;
    return;
  }
  bid -= 8192;
  const float* in; u16* out; int R, C, local;
  if (bid < 4096) {
    int m = bid >> 10;
    in  = m == 0 ? wq  : (m == 1 ? wk  : (m == 2 ? wv  : wo));
    out = m == 0 ? wqT : (m == 1 ? wkT : (m == 2 ? wvT : woT));
    R = 1024; C = 1024; local = bid & 1023;
  } else if (bid < 8192) {
    in = w1; out = w1T; R = 1024; C = 4096; local = bid - 4096;
  } else {
    in = w2; out = w2T; R = 4096; C = 1024; local = bid - 8192;
  }
  const int ctiles = C >> 5;
  const int c0 = (local % ctiles) * 32;
  const int r0 = (local / ctiles) * 32;
  const int xx = tid & 31, yy = tid >> 5;
  __shared__ float t[32][33];
#pragma unroll
  for (int i = 0; i < 4; ++i)
    t[yy + i*8][xx] = in[(long)(r0 + yy + i*8) * C + c0 + xx];
  __syncthreads();
#pragma unroll
  for (int i = 0; i < 4; ++i)
    out[(long)(c0 + yy + i*8) * R + r0 + xx] = f2b(t[xx][yy + i*8]);
}

// ===== gemm10c (proven best): 8 waves, 64x64/wave, ring-of-3, vmcnt(3),
//       single barrier/K-step, 2 blocks/CU =====
// EPI: 0 = bf16+bias, 2 = tanh-GELU, 3 = fused-QKV routing (V direct-transposed
//      to C2 = vT [B,H,HD,S]), 4 = bf16+bias+residual(res)
template<int EPI, int WN>
__global__ __launch_bounds__(512, 2) void gemm10(
    const u16* __restrict__ A, const u16* __restrict__ BT,
    const float* __restrict__ bias0, const float* __restrict__ bias1,
    const float* __restrict__ bias2,
    u16* __restrict__ C0, u16* __restrict__ C1, u16* __restrict__ C2,
    const u16* __restrict__ res,
    int Ndim, int Kdim)
{
  constexpr int BM = (WN == 4) ? 128 : 256;
  constexpr int BN = WN * 64;
  constexpr int SLOT = (BM + BN) * 64;   // 24576 bytes
  __shared__ char lds[3 * SLOT];
  const int tid = threadIdx.x;
  const int w = tid >> 6, lane = tid & 63;
  const int lr = lane & 15, lg = lane >> 4;
  const int wm = w / WN, wn = w % WN;

  const int nbx = Ndim / BN;
  const int cpx = gridDim.x >> 3;
  const int bid = blockIdx.x;
  const int swzb = (bid & 7) * cpx + (bid >> 3);
  const long blockM = (long)(swzb / nbx) * BM;
  const long blockN = (long)(swzb % nbx) * BN;

  const int srow = tid >> 2;
  const int scol = ((tid & 3) * 16) ^ SWZ64(srow);
  const u16* Ag  = A  + (blockM + srow) * (long)Kdim + (scol >> 1);
  const u16* Ag2 = Ag + (long)128 * Kdim;
  const u16* Bg  = BT + (blockN + srow) * (long)Kdim + (scol >> 1);
  const u16* Bg2 = Bg + (long)128 * Kdim;

  auto STAGE = [&](int slot, long ko) {
    char* base = &lds[slot * SLOT];
    gl_lds16(Ag + ko, base + w * 1024);
    if constexpr (WN == 2) gl_lds16(Ag2 + ko, base + 8192 + w * 1024);
    gl_lds16(Bg + ko, base + BM * 64 + w * 1024);
    if constexpr (WN == 4) gl_lds16(Bg2 + ko, base + BM * 64 + 8192 + w * 1024);
  };

  const int rsw = (lg * 16) ^ SWZ64(lr);
  int offA[4], offB[4];
#pragma unroll
  for (int mf = 0; mf < 4; ++mf) offA[mf] = (wm*64 + mf*16 + lr) * 64 + rsw;
#pragma unroll
  for (int nf = 0; nf < 4; ++nf) offB[nf] = BM*64 + (wn*64 + nf*16 + lr) * 64 + rsw;

  f32x4 acc[4][4] = {};
  const int NS = Kdim >> 5;

  STAGE(0, 0);
  STAGE(1, 32);
  asm volatile("s_waitcnt vmcnt(3)" ::: "memory");
  __builtin_amdgcn_s_barrier();

  int sl = 0, sl2 = 2;
  for (int t = 0; t < NS; ++t) {
    const char* s = &lds[sl * SLOT];
    bf16x8 af[4], bfr[4];
#pragma unroll
    for (int mf = 0; mf < 4; ++mf) af[mf] = *(const bf16x8*)(s + offA[mf]);
#pragma unroll
    for (int nf = 0; nf < 4; ++nf) bfr[nf] = *(const bf16x8*)(s + offB[nf]);
    if (t + 2 < NS) {
      STAGE(sl2, (long)(t + 2) * 32);
      asm volatile("s_waitcnt vmcnt(3)" ::: "memory");
    } else if (t == NS - 2) {
      asm volatile("s_waitcnt vmcnt(0)" ::: "memory");
    }
    __builtin_amdgcn_s_barrier();   // single barrier per K-step
    __builtin_amdgcn_s_setprio(1);
#pragma unroll
    for (int mf = 0; mf < 4; ++mf)
#pragma unroll
      for (int nf = 0; nf < 4; ++nf)
        acc[mf][nf] = MFMA16(bfr[nf], af[mf], acc[mf][nf], 0, 0, 0);
    __builtin_amdgcn_s_setprio(0);
    sl  = (sl  == 2) ? 0 : sl  + 1;
    sl2 = (sl2 == 2) ? 0 : sl2 + 1;
  }

  const float* bsel = bias0;
  u16* osel = C0;
  long nstride = Ndim;
  long ncol0 = blockN;
  int mat = 0;
  if (EPI == 3) {
    mat = (int)(blockN >> 10);
    bsel = mat == 0 ? bias0 : (mat == 1 ? bias1 : bias2);
    osel = mat == 0 ? C0 : C1;
    nstride = 1024;
    ncol0 = blockN & 1023;
  }
  __syncthreads();   // all waves done with K-loop LDS reads

  if (EPI == 3 && mat == 2) {
    // ---- V: direct transposed store to vT [B,H,HD,S] (C2) ----
#pragma unroll
    for (int mf = 0; mf < 4; ++mf) {
      const int row = wm*64 + mf*16 + lr;
      const long m = blockM + row;
      const long b = m >> 11, sg = m & 2047;
#pragma unroll
      for (int nf = 0; nf < 4; ++nf) {
#pragma unroll
        for (int j = 0; j < 4; ++j) {
          const long colg = ncol0 + wn*64 + nf*16 + lg*4 + j;
          float v = acc[mf][nf][j] + bsel[colg];
          const long h = colg >> 6, hd = colg & 63;
          C2[((b*16 + h)*64 + hd)*2048 + sg] = f2b(v);
        }
      }
    }
    return;
  }

  constexpr int RB = BN * 2;
  char* const et = &lds[0];
#pragma unroll
  for (int mf = 0; mf < 4; ++mf) {
    const int row = wm*64 + mf*16 + lr;
#pragma unroll
    for (int nf = 0; nf < 4; ++nf) {
      const int colu = wn*64 + nf*16 + lg*4;
      float4 bv = *(const float4*)&bsel[ncol0 + colu];
      float v0 = acc[mf][nf][0] + bv.x;
      float v1 = acc[mf][nf][1] + bv.y;
      float v2 = acc[mf][nf][2] + bv.z;
      float v3 = acc[mf][nf][3] + bv.w;
      if (EPI == 2) {
        v0 = gelu_t(v0); v1 = gelu_t(v1); v2 = gelu_t(v2); v3 = gelu_t(v3);
      }
      if (EPI == 4) {
        ushort4 rv = *(const ushort4*)&res[(blockM + row) * 1024 + ncol0 + colu];
        v0 += b2f(rv.x); v1 += b2f(rv.y); v2 += b2f(rv.z); v3 += b2f(rv.w);
      }
      ushort4 st;
      st.x = f2b(v0); st.y = f2b(v1); st.z = f2b(v2); st.w = f2b(v3);
      *(ushort4*)(et + row*RB + ((colu*2) ^ ((row & 7) << 4))) = st;
    }
  }
  __syncthreads();
  constexpr int CHR  = RB / 16;
  constexpr int ITER = BM * CHR / 512;
#pragma unroll
  for (int i = 0; i < ITER; ++i) {
    const int idx = i*512 + tid;
    const int row = idx / CHR;
    const int cb  = (idx % CHR) * 16;
    uint4 val = *(const uint4*)(et + row*RB + (cb ^ ((row & 7) << 4)));
    *(uint4*)&osel[(blockM + row) * nstride + ncol0 + (cb >> 1)] = val;
  }
}

// ========== flash attention v8 (proven 88.6us): QBLK=256 + per-head XCD clustering ==========
__device__ __forceinline__ void packp(const float* p, bf16x8* pfo) {
#pragma unroll
  for (int ks = 0; ks < 2; ++ks) {
    uint4 uu;
    uu.x = cvtpk(p[ks*4+0], p[ks*4+1]);
    uu.y = cvtpk(p[ks*4+2], p[ks*4+3]);
    uu.z = cvtpk(p[(ks+2)*4+0], p[(ks+2)*4+1]);
    uu.w = cvtpk(p[(ks+2)*4+2], p[(ks+2)*4+3]);
    pfo[ks] = __builtin_bit_cast(bf16x8, uu);
  }
}

__device__ __forceinline__ void sm_uni(const f32x4* s, float bu, bf16x8* pfo) {
  float p[16];
#pragma unroll
  for (int ni = 0; ni < 4; ++ni)
#pragma unroll
    for (int j = 0; j < 4; ++j)
      p[ni*4+j] = exp2_fast(fmaf(s[ni][j], A_CONST, bu));
  packp(p, pfo);
}

__device__ __forceinline__ void sm_slow(const f32x4* s, const float* relb,
                                        int rbase, bf16x8* pfo) {
  float p[16];
#pragma unroll
  for (int ni = 0; ni < 4; ++ni) {
    const int koff = (ni&1)*32 + (ni>>1)*4;
#pragma unroll
    for (int j = 0; j < 4; ++j) {
      int idx = med3i(rbase + koff + j + MR_, 0, 2*MR_);
      p[ni*4+j] = exp2_fast(fmaf(s[ni][j], A_CONST, relb[idx]));
    }
  }
  packp(p, pfo);
}

__global__ __launch_bounds__(256, 2) void attn8_kernel(
    const u16* __restrict__ q, const u16* __restrict__ k,
    const u16* __restrict__ vT, const float* __restrict__ rel_pos,
    u16* __restrict__ ao)
{
  __shared__ u16 SM[16384];
  __shared__ float relb[2*MR_ + 1];

  const int tid = threadIdx.x;
  const int w = tid >> 6, lane = tid & 63;
  const int lr = lane & 15, lg = lane >> 4;
  const int bid = blockIdx.x;
  const int bh = ((bid >> 6) << 3) | (bid & 7);
  const int qt = (bid >> 3) & 7;
  const int b = bh >> 4, h = bh & 15;
  const int q0 = qt * 256;
  const int qlo = q0 + w*64;

  if (tid < 2*MR_ + 1) relb[tid] = rel_pos[h * (2*MR_ + 1) + tid] * LOG2E_;

  const int srow0 = w*8 + (lane >> 3);
  const int srow1 = 32 + srow0;
  const int scb   = (lane & 7) * 16;
  const int col0  = scb ^ SWZ(srow0);
  const int col1  = scb ^ SWZ(srow1);

  const long qkbase = ((long)(b*S_)) * D_ + h*64;
  const long vbase  = ((long)((b*H_ + h) * HD_)) * S_;

  {
    const u16* qg = q + qkbase + (long)q0 * D_;
#pragma unroll
    for (int c = 0; c < 8; ++c)
      gl_lds16(qg + (long)(c*32 + srow0)*D_ + (col0 >> 1), &SM[(c*32 + w*8)*64]);
  }
  __syncthreads();
  bf16x8 qf[4][2];
#pragma unroll
  for (int qi = 0; qi < 4; ++qi)
#pragma unroll
    for (int ks = 0; ks < 2; ++ks) {
      int row = w*64 + qi*16 + lr;
      qf[qi][ks] = *(const bf16x8*)((const char*)&SM[0] + row*128 + ((ks*64 + lg*16) ^ SWZ(row)));
    }
  const float bHI = relb[2*MR_];
  const float bLO = relb[0];
  __syncthreads();

  int offK0[4], offV0[4];
#pragma unroll
  for (int ni = 0; ni < 4; ++ni) {
    int kr = (ni&1)*32 + (lr>>2)*8 + (ni>>1)*4 + (lr&3);  // kappa(ni, lr)
    int vr = ni*16 + lr;
    offK0[ni] = kr*128 + ((lg*16) ^ SWZ(kr));
    offV0[ni] = vr*128 + ((lg*16) ^ SWZ(vr));
  }

  const u16* kp0 = k  + qkbase + (long)srow0*D_ + (col0 >> 1);
  const u16* kp1 = k  + qkbase + (long)srow1*D_ + (col1 >> 1);
  const u16* vp0 = vT + vbase  + (long)srow0*S_ + (col0 >> 1);
  const u16* vp1 = vT + vbase  + (long)srow1*S_ + (col1 >> 1);
  u16* kb_w0 = &SM[(w*8)*64];
  u16* kb_w1 = &SM[(32 + w*8)*64];
  u16* vb_w0 = &SM[8192 + (w*8)*64];
  u16* vb_w1 = &SM[8192 + (32 + w*8)*64];

  bf16x8 onesf;
#pragma unroll
  for (int i = 0; i < 8; ++i) onesf[i] = (short)0x3F80;

  f32x4 acco[4][4] = {};
  f32x4 accl[4] = {};

  gl_lds16(kp0, kb_w0);
  gl_lds16(kp1, kb_w1);
  gl_lds16(vp0, vb_w0);
  gl_lds16(vp1, vb_w1);

  const long kstep = (long)64 * D_;
  const int NT = S_ / 64;
  for (int t = 0; t < NT; ++t) {
    const int cur = t & 1;
    __syncthreads();
    if (t + 1 < NT) {
      int bufo = (cur ^ 1) * 4096;
      gl_lds16(kp0 + (long)(t+1)*kstep, kb_w0 + bufo);
      gl_lds16(kp1 + (long)(t+1)*kstep, kb_w1 + bufo);
      gl_lds16(vp0 + (t+1)*64, vb_w0 + bufo);
      gl_lds16(vp1 + (t+1)*64, vb_w1 + bufo);
    }
    const char* Kb = (const char*)&SM[cur * 4096];
    const char* Vb = (const char*)&SM[8192 + cur * 4096];
    const int k0 = t * 64;

    f32x4 sc[4][4] = {};
#pragma unroll
    for (int ks = 0; ks < 2; ++ks)
#pragma unroll
      for (int ni = 0; ni < 4; ++ni) {
        bf16x8 kf = *(const bf16x8*)(Kb + (offK0[ni] ^ (ks*64)));
#pragma unroll
        for (int qi = 0; qi < 4; ++qi)
          sc[qi][ni] = MFMA16(kf, qf[qi][ks], sc[qi][ni], 0, 0, 0);
      }

    bf16x8 pf[4][2];
    bool hi_u = (k0 - (qlo + 63)) >= MR_;
    bool lo_u = (qlo - (k0 + 63)) >= MR_;
    if (hi_u || lo_u) {
      float bu = hi_u ? bHI : bLO;
#pragma unroll
      for (int qi = 0; qi < 4; ++qi) sm_uni(sc[qi], bu, pf[qi]);
    } else {
      int rb0 = k0 + lg*8 - (qlo + lr);
#pragma unroll
      for (int qi = 0; qi < 4; ++qi) sm_slow(sc[qi], relb, rb0 - qi*16, pf[qi]);
    }

#pragma unroll
    for (int ks = 0; ks < 2; ++ks) {
#pragma unroll
      for (int ni = 0; ni < 4; ++ni) {
        bf16x8 vf = *(const bf16x8*)(Vb + (offV0[ni] ^ (ks*64)));
#pragma unroll
        for (int qi = 0; qi < 4; ++qi)
          acco[qi][ni] = MFMA16(vf, pf[qi][ks], acco[qi][ni], 0, 0, 0);
      }
#pragma unroll
      for (int qi = 0; qi < 4; ++qi)
        accl[qi] = MFMA16(onesf, pf[qi][ks], accl[qi], 0, 0, 0);
    }
  }

#pragma unroll
  for (int qi = 0; qi < 4; ++qi) {
    float inv = 1.0f / accl[qi][0];
    long orow = ((long)(b*S_ + qlo + qi*16 + lr)) * D_ + h*64;
#pragma unroll
    for (int ni = 0; ni < 4; ++ni) {
      ushort4 ov;
      ov.x = f2b(acco[qi][ni][0] * inv);
      ov.y = f2b(acco[qi][ni][1] * inv);
      ov.z = f2b(acco[qi][ni][2] * inv);
      ov.w = f2b(acco[qi][ni][3] * inv);
      *(ushort4*)(ao + orow + ni*16 + lg*4) = ov;
    }
  }
}

// ------------- single-input RMSNorm (input already includes residual) -------------
template<int OUTF>
__global__ __launch_bounds__(256) void rms1_kernel(
    const u16* __restrict__ a, const float* __restrict__ g,
    float* __restrict__ outf, u16* __restrict__ outb)
{
  long row = blockIdx.x;
  int tid = threadIdx.x;
  ushort4 av = ((const ushort4*)a)[row*256 + tid];
  float y[4] = { b2f(av.x), b2f(av.y), b2f(av.z), b2f(av.w) };
  float ss = 0.f;
#pragma unroll
  for (int i = 0; i < 4; ++i) ss += y[i]*y[i];
#pragma unroll
  for (int m = 1; m < 64; m <<= 1) ss += __shfl_xor(ss, m);
  __shared__ float red[4];
  int w = tid >> 6, lane = tid & 63;
  if (lane == 0) red[w] = ss;
  __syncthreads();
  ss = red[0] + red[1] + red[2] + red[3];
  float rinv = rsqrtf(ss * (1.0f / D_) + 1e-5f);
  float4 gv = ((const float4*)g)[tid];
  float o[4] = { y[0]*rinv*gv.x, y[1]*rinv*gv.y, y[2]*rinv*gv.z, y[3]*rinv*gv.w };
  if (OUTF) {
    float4 of = { o[0], o[1], o[2], o[3] };
    ((float4*)outf)[row*256 + tid] = of;
  } else {
    ushort4 ob;
    ob.x = f2b(o[0]); ob.y = f2b(o[1]); ob.z = f2b(o[2]); ob.w = f2b(o[3]);
    ((ushort4*)outb)[row*256 + tid] = ob;
  }
}

extern "C" void kernel_launch(void* const* d_in, const int* in_sizes, int n_in,
                              void* d_out, int out_size, void* d_ws, size_t ws_size,
                              hipStream_t stream) {
  const float* x   = (const float*)d_in[0];
  const float* g1  = (const float*)d_in[1];
  const float* g2  = (const float*)d_in[2];
  const float* wq  = (const float*)d_in[3];
  const float* bq  = (const float*)d_in[4];
  const float* wk  = (const float*)d_in[5];
  const float* bk  = (const float*)d_in[6];
  const float* wv  = (const float*)d_in[7];
  const float* bv  = (const float*)d_in[8];
  const float* wo  = (const float*)d_in[9];
  const float* bo  = (const float*)d_in[10];
  const float* rel = (const float*)d_in[11];
  const float* w1  = (const float*)d_in[12];
  const float* b1  = (const float*)d_in[13];
  const float* w2  = (const float*)d_in[14];
  const float* b2  = (const float*)d_in[15];
  float* out = (float*)d_out;

  char* ws = (char*)d_ws;
  const size_t MB = 1024ull * 1024ull;
  u16* xb   = (u16*)(ws + 0);        // 16 MB
  u16* wqT  = (u16*)(ws + 16*MB);    // 2  } contiguous [3072][1024]
  u16* wkT  = (u16*)(ws + 18*MB);    // 2  }
  u16* wvT  = (u16*)(ws + 20*MB);    // 2  }
  u16* woT  = (u16*)(ws + 22*MB);    // 2
  u16* w1T  = (u16*)(ws + 24*MB);    // 8
  u16* w2T  = (u16*)(ws + 32*MB);    // 8
  u16* qb   = (u16*)(ws + 40*MB);    // 16
  u16* kb   = (u16*)(ws + 56*MB);    // 16
  u16* vTb  = (u16*)(ws + 88*MB);    // 16 (written directly by QKV epilogue)
  u16* aob  = (u16*)(ws + 104*MB);   // 16
  u16* prjb = (u16*)(ws + 120*MB);   // 16  (= proj + x, residual fused)
  u16* x1b  = (u16*)(ws + 136*MB);   // 16
  u16* hb   = (u16*)(ws + 40*MB);    // 64, reuses q/k/vT (dead after attention)
  u16* ffb  = (u16*)(ws + 120*MB);   // 16, reuses prjb (= ff + x1, residual fused)
  (void)ws_size; (void)in_sizes; (void)n_in; (void)out_size;

  // 1. merged prep: cvt + all 6 weight transposes (one launch)
  prep_kernel<<<20480, 256, 0, stream>>>(
      x, xb, wq, wk, wv, wo, w1, w2, wqT, wkT, wvT, woT, w1T, w2T);

  // 2. fused QKV projection; V stored transposed directly to vTb
  gemm10<3,4><<<(3072/256)*(M_/128), 512, 0, stream>>>(
      xb, wqT, bq, bk, bv, qb, kb, vTb, nullptr, 3072, D_);

  // 3. attention: QBLK=256, 1D grid 512, per-head XCD clustering
  attn8_kernel<<<512, 256, 0, stream>>>(qb, kb, vTb, rel, aob);

  // 4. output projection + residual(xb): prjb = ao@wo + bo + x
  gemm10<4,2><<<(D_/128)*(M_/256), 512, 0, stream>>>(
      aob, woT, bo, nullptr, nullptr, prjb, nullptr, nullptr, xb, D_, D_);

  // 5. x1 = rmsnorm(prjb, g1) -> bf16
  rms1_kernel<0><<<M_, 256, 0, stream>>>(prjb, g1, nullptr, x1b);

  // 6. h = gelu(x1 @ w1 + b1): BM=128, BN=256, grid 1024
  gemm10<2,4><<<(DFF_/256)*(M_/128), 512, 0, stream>>>(
      x1b, w1T, b1, nullptr, nullptr, hb, nullptr, nullptr, nullptr, DFF_, D_);

  // 7. ffb = h @ w2 + b2 + x1 (residual fused)
  gemm10<4,2><<<(D_/128)*(M_/256), 512, 0, stream>>>(
      hb, w2T, b2, nullptr, nullptr, ffb, nullptr, nullptr, x1b, D_, DFF_);

  // 8. out = rmsnorm(ffb, g2) -> f32 d_out
  rms1_kernel<1><<<M_, 256, 0, stream>>>(ffb, g2, out, nullptr);
}